// Round 13
// baseline (308.088 us; speedup 1.0000x reference)
//
#include <hip/hip_runtime.h>
#include <math.h>

#define S_LEN 1024
#define DMODEL 1024
#define NH 16
#define HD 64
#define P2 512
#define BATCH 4

typedef unsigned short u16;
typedef unsigned char u8;
typedef __attribute__((ext_vector_type(8))) short short8;
typedef __attribute__((ext_vector_type(4))) float floatx4;

__device__ __forceinline__ u16 f2bf(float f) {
  unsigned u = __float_as_uint(f);
  unsigned r = u + 0x7FFFu + ((u >> 16) & 1u);
  return (u16)(r >> 16);
}
__device__ __forceinline__ float bf2f(u16 v) {
  return __uint_as_float(((unsigned)v) << 16);
}
__device__ __forceinline__ unsigned pk2bf(float a, float b) {
#if __has_builtin(__builtin_amdgcn_cvt_pk_bf16_f32)
  typedef __attribute__((ext_vector_type(2))) __bf16 bf2v;
  bf2v t = __builtin_amdgcn_cvt_pk_bf16_f32(a, b);
  return *(unsigned*)&t;
#else
  return (unsigned)f2bf(a) | ((unsigned)f2bf(b) << 16);
#endif
}
// e5m2-as-top-byte-of-f16: encode via v_cvt_f16_f32 (+round-half-up on bit 7)
__device__ __forceinline__ u8 f2e5(float x) {
  union { _Float16 h; u16 u; } c;
  c.h = (_Float16)x;
  return (u8)(((unsigned)c.u + 0x80u) >> 8);
}
__device__ __forceinline__ float e52f(u8 b) {
  union { u16 u; _Float16 h; } c;
  c.u = (u16)b << 8;
  return (float)c.h;
}
// async global->LDS, 16B per lane; lds dest = wave-uniform base + lane*16
__device__ __forceinline__ void gl_lds16(const void* g, void* l) {
  __builtin_amdgcn_global_load_lds(
      (const __attribute__((address_space(1))) void*)g,
      (__attribute__((address_space(3))) void*)l, 16, 0, 0);
}

// ---------------- fused cast + prep (tab/biascat in the tail blocks) ---------
__global__ __launch_bounds__(256) void cast_all(
    const float* __restrict__ h, const float* __restrict__ r,
    const float* __restrict__ wq, const float* __restrict__ wk,
    const float* __restrict__ wv, const float* __restrict__ wo,
    u16* __restrict__ hb, u16* __restrict__ rb,
    u16* __restrict__ wqkvb, u16* __restrict__ wob,
    int* __restrict__ tab, const float* __restrict__ bq,
    const float* __restrict__ bk, const float* __restrict__ bv,
    float* __restrict__ biascat) {
  int b = blockIdx.x;
  if (b >= 8704) {  // prep tail: 16 blocks
    int t = (b - 8704) * 256 + threadIdx.x;
    if (t < 2 * S_LEN - 1) {
      int rel = t - (S_LEN - 1);
      const int mid = 128;
      float abspos = (rel < mid && rel > -mid) ? (float)(mid - 1) : fabsf((float)rel);
      float bucket;
      if (abspos <= (float)mid) {
        bucket = (float)rel;
      } else {
        float den = (float)log(3.9921875);
        float lp = ceilf(logf(abspos / 128.0f) / den * 127.0f) + 128.0f;
        bucket = (rel > 0) ? lp : -lp;
      }
      int idx = (int)bucket + 256;
      idx = idx < 0 ? 0 : (idx > P2 - 1 ? P2 - 1 : idx);
      tab[t] = idx;
    }
    if (t < 3072) biascat[t] = t < 1024 ? bq[t] : (t < 2048 ? bk[t - 1024] : bv[t - 2048]);
    return;
  }
  const float* src;
  u16* dst;
  int off;
  if (b < 4096) { src = h; dst = hb; off = b; }
  else if (b < 4608) { src = r; dst = rb; off = b - 4096; }
  else if (b < 5632) { src = wq; dst = wqkvb; off = b - 4608; }
  else if (b < 6656) { src = wk; dst = wqkvb + 1024 * 1024; off = b - 5632; }
  else if (b < 7680) { src = wv; dst = wqkvb + 2 * 1024 * 1024; off = b - 6656; }
  else { src = wo; dst = wob; off = b - 7680; }
  long i = (long)off * 1024 + (threadIdx.x << 2);
  float4 v = *(const float4*)(src + i);
  uint2 o;
  o.x = pk2bf(v.x, v.y);
  o.y = pk2bf(v.z, v.w);
  *(uint2*)(dst + i) = o;
}

// ---------------- bf16 MFMA NT GEMM body, 128x128 tile, BK=64 (r11) ----------
__device__ __forceinline__ void mgemm_body(
    u16* Al, u16* Bl, const u16* A, const u16* Bw,
    const float* b0, const float* resid, void* out0,
    int M, int N, int K, int mode, int bx, int by, int tid) {
  const int wave = tid >> 6, lane = tid & 63;
  const int quad = lane >> 4, l16 = lane & 15;
  const int m0 = by * 128, n0 = bx * 128;

  const floatx4 fzero = {0.f, 0.f, 0.f, 0.f};
  floatx4 acc[4][4];
#pragma unroll
  for (int mi = 0; mi < 4; ++mi)
#pragma unroll
    for (int ni = 0; ni < 4; ++ni) acc[mi][ni] = fzero;

  const int wm = (wave & 1) * 64, wn = (wave >> 1) * 64;

  for (int k0 = 0; k0 < K; k0 += 64) {
#pragma unroll
    for (int i = 0; i < 4; ++i) {
      int ch = i * 256 + tid;
      int row = ch >> 3, c = ch & 7, cs = c ^ (row & 7);
      gl_lds16(A + (long)(m0 + row) * K + k0 + cs * 8, Al + ch * 8);
      gl_lds16(Bw + (long)(n0 + row) * K + k0 + cs * 8, Bl + ch * 8);
    }
    __syncthreads();
    short8 af[4][2], bf[4][2];
#pragma unroll
    for (int t = 0; t < 4; ++t)
#pragma unroll
      for (int kk = 0; kk < 2; ++kk) {
        int sw = (((kk * 4 + quad) ^ (l16 & 7)) << 3);
        af[t][kk] = *(const short8*)(Al + (wm + t * 16 + l16) * 64 + sw);
        bf[t][kk] = *(const short8*)(Bl + (wn + t * 16 + l16) * 64 + sw);
      }
#pragma unroll
    for (int kk = 0; kk < 2; ++kk)
#pragma unroll
      for (int mi = 0; mi < 4; ++mi)
#pragma unroll
        for (int ni = 0; ni < 4; ++ni)
          acc[mi][ni] =
              __builtin_amdgcn_mfma_f32_16x16x32_bf16(af[mi][kk], bf[ni][kk], acc[mi][ni], 0, 0, 0);
    __syncthreads();
  }

  if (mode == 0) {
    float* o = (float*)out0;
#pragma unroll
    for (int mi = 0; mi < 4; ++mi)
#pragma unroll
      for (int ni = 0; ni < 4; ++ni) {
        int n = n0 + wn + ni * 16 + l16;
#pragma unroll
        for (int r = 0; r < 4; ++r) {
          int m = m0 + wm + mi * 16 + quad * 4 + r;
          o[(long)m * N + n] = acc[mi][ni][r] + b0[n] + resid[(long)m * N + n];
        }
      }
  } else {
    u16* o = (u16*)out0;
    u16* T = Al;  // 32 x 132 u16 = 8448 B (Al dead in epilogue)
    const int wp = wave & 1;
    float biasv[4];
#pragma unroll
    for (int ni = 0; ni < 4; ++ni) biasv[ni] = b0[n0 + wn + ni * 16 + l16];
#pragma unroll
    for (int p = 0; p < 4; ++p) {
#pragma unroll
      for (int ni = 0; ni < 4; ++ni) {
        int cl = wn + ni * 16 + l16;
#pragma unroll
        for (int r = 0; r < 4; ++r)
          T[(wp * 16 + quad * 4 + r) * 132 + cl] = f2bf(acc[p][ni][r] + biasv[ni]);
      }
      __syncthreads();
#pragma unroll
      for (int u = 0; u < 4; ++u) {
        int ch = u * 256 + tid;
        int row = ch >> 5, c4 = (ch & 31) << 2;
        int gr = m0 + (row >> 4) * 64 + p * 16 + (row & 15);
        *(ushort4*)(o + (long)gr * N + n0 + c4) = *(const ushort4*)(T + row * 132 + c4);
      }
      if (p < 3) __syncthreads();
    }
  }
}

// fused QKV + pos projections (T1 chunked XCD swizzle; measured neutral, free)
__global__ __launch_bounds__(256) void mgemm_qkvpos(
    const u16* __restrict__ hid, const u16* __restrict__ rel,
    const u16* __restrict__ wqkv, const float* __restrict__ biascat,
    u16* __restrict__ qkv, u16* __restrict__ posm) {
  __shared__ u16 Al[128 * 64];
  __shared__ u16 Bl[128 * 64];
  int id0 = blockIdx.x;
  int id = (id0 & 7) * 104 + (id0 >> 3);  // chunked per-XCD remap
  if (id < 768) {
    mgemm_body(Al, Bl, hid, wqkv, biascat, nullptr, qkv, 4096, 3072, 1024, 1,
               id % 24, id / 24, threadIdx.x);
  } else {
    int t = id - 768;
    mgemm_body(Al, Bl, rel, wqkv, biascat, nullptr, posm, 512, 2048, 1024, 1,
               t % 16, t / 16, threadIdx.x);
  }
}

// ---------------- out-proj GEMM: 64x128 tile, 2 blocks/CU (r15) --------------
__global__ __launch_bounds__(256) void mgemm_op(
    const u16* __restrict__ A, const u16* __restrict__ Bw,
    const float* __restrict__ b0, const float* __restrict__ resid,
    float* __restrict__ o, int M, int N, int K) {
  __shared__ u16 Al[64 * 64];    // A tile: 64 rows x 64 k
  __shared__ u16 Bl[128 * 64];   // B tile: 128 n-rows x 64 k
  const int tid = threadIdx.x;
  const int wave = tid >> 6, lane = tid & 63;
  const int quad = lane >> 4, l16 = lane & 15;
  const int m0 = blockIdx.y * 64, n0 = blockIdx.x * 128;
  const int wn = wave * 32;

  const floatx4 fzero = {0.f, 0.f, 0.f, 0.f};
  floatx4 acc[4][2];
#pragma unroll
  for (int mi = 0; mi < 4; ++mi)
#pragma unroll
    for (int ni = 0; ni < 2; ++ni) acc[mi][ni] = fzero;

  for (int k0 = 0; k0 < K; k0 += 64) {
#pragma unroll
    for (int i = 0; i < 2; ++i) {  // A: 64 rows x 8 chunks = 512
      int ch = i * 256 + tid;
      int row = ch >> 3, c = ch & 7, cs = c ^ (row & 7);
      gl_lds16(A + (long)(m0 + row) * K + k0 + cs * 8, Al + ch * 8);
    }
#pragma unroll
    for (int i = 0; i < 4; ++i) {  // B: 128 rows x 8 chunks = 1024
      int ch = i * 256 + tid;
      int row = ch >> 3, c = ch & 7, cs = c ^ (row & 7);
      gl_lds16(Bw + (long)(n0 + row) * K + k0 + cs * 8, Bl + ch * 8);
    }
    __syncthreads();
    short8 af[4][2], bf[2][2];
#pragma unroll
    for (int kk = 0; kk < 2; ++kk) {
      int sw = (((kk * 4 + quad) ^ (l16 & 7)) << 3);
#pragma unroll
      for (int t = 0; t < 4; ++t)
        af[t][kk] = *(const short8*)(Al + (t * 16 + l16) * 64 + sw);
#pragma unroll
      for (int ni = 0; ni < 2; ++ni)
        bf[ni][kk] = *(const short8*)(Bl + (wn + ni * 16 + l16) * 64 + sw);
    }
#pragma unroll
    for (int kk = 0; kk < 2; ++kk)
#pragma unroll
      for (int mi = 0; mi < 4; ++mi)
#pragma unroll
        for (int ni = 0; ni < 2; ++ni)
          acc[mi][ni] =
              __builtin_amdgcn_mfma_f32_16x16x32_bf16(af[mi][kk], bf[ni][kk], acc[mi][ni], 0, 0, 0);
    __syncthreads();
  }

#pragma unroll
  for (int mi = 0; mi < 4; ++mi)
#pragma unroll
    for (int ni = 0; ni < 2; ++ni) {
      int n = n0 + wn + ni * 16 + l16;
#pragma unroll
      for (int r = 0; r < 4; ++r) {
        int m = m0 + mi * 16 + quad * 4 + r;
        o[(long)m * N + n] = acc[mi][ni][r] + b0[n] + resid[(long)m * N + n];
      }
    }
}

// ---------------- gbias (r9/r13 measured-best, FROZEN) + vtrans tail ---------
// Every deviation from this config failed (r10 packed stores, r11 stride-70,
// r12 merged loops, r14 e5m2-LDS/6-blocks-CU): bf16 windows stride 68,
// separate Gq/Gk loops, strided-k gather, scalar byte stores, 4 blocks/CU.
// blocks [16384,17408): V transpose (tile aliases U).
__global__ __launch_bounds__(256, 4) void gbias_vt(
    const u16* __restrict__ qkv, const u16* __restrict__ pos,
    const int* __restrict__ tab, u8* __restrict__ Sb, u16* __restrict__ Vt) {
  __shared__ u16 U[128 * 68];    // phase 1: Qs/Ks; phase 2: CsT; vtrans: tile
  __shared__ u16 DsT[128 * 68];  // Gk^T [off][kloc]
  __shared__ u16 offL[128];

  const int tid = threadIdx.x;
  const int id = blockIdx.x;

  if (id >= 16384) {  // ---- vtrans tail ----
    int v = id - 16384;
    const int s0 = (v & 15) * 64, h = (v >> 4) & 15, b = v >> 8;
    u16(*tile)[68] = (u16(*)[68])U;  // 64x68 u16 = 8704 B
    const int r16 = tid >> 4, c4 = (tid & 15) << 2;
    const u16* src = qkv + ((long)(b * S_LEN + s0)) * 3072 + 2048 + h * HD;
#pragma unroll
    for (int i = 0; i < 4; ++i) {
      int row = i * 16 + r16;
      ushort4 vv = *(const ushort4*)(src + (long)row * 3072 + c4);
      *(ushort4*)&tile[row][c4] = vv;
    }
    __syncthreads();
    u16* dst = Vt + ((long)(b * NH + h) * HD) * S_LEN + s0;
#pragma unroll
    for (int i = 0; i < 4; ++i) {
      int dd = i * 16 + r16;
      ushort4 o;
      o.x = tile[c4 + 0][dd]; o.y = tile[c4 + 1][dd];
      o.z = tile[c4 + 2][dd]; o.w = tile[c4 + 3][dd];
      *(ushort4*)(dst + (long)dd * S_LEN + c4) = o;
    }
    return;
  }

  u16* Qs = U;
  u16* Ks = U + 64 * 64;
  u16* CsT = U;

  const int wave = tid >> 6, lane = tid & 63;
  const int quad = lane >> 4, l16 = lane & 15;
  const int g = id & 63, tt = id >> 6;  // id%8==g%8 -> XCD affinity
  const int qi = tt >> 4, ki = tt & 15;
  const int b = g >> 4, h = g & 15;
  const int q0 = qi * 64, k0 = ki * 64;

  const u16* Qg = qkv + ((long)(b * S_LEN + q0)) * 3072 + h * HD;
  const u16* Kg = qkv + ((long)(b * S_LEN + k0)) * 3072 + 1024 + h * HD;
  const u16* posq_g = pos + h * HD;         // Wq-proj cols
  const u16* posk_g = pos + 1024 + h * HD;  // Wk-proj cols

  const int dmin = q0 - k0 - 63;
  const int base = tab[dmin + 1023];
  const int w = tab[dmin + 1149] - base + 1;  // monotone => 1..127
  const int nsl = (w + 15) >> 4;
  const bool lin = (w == 127);
  if (!lin && tid < 127) offL[tid] = (u16)(tab[dmin + 1023 + tid] - base);

  // stage Q,K async; source chunk-swizzled (c ^ row&7) for 2-way b128 reads
#pragma unroll
  for (int i = 0; i < 2; ++i) {
    int ch = i * 256 + wave * 64 + lane;
    int row = ch >> 3, c = ch & 7, cs = c ^ (row & 7);
    gl_lds16(Qg + (long)row * 3072 + cs * 8, Qs + (i * 256 + wave * 64) * 8);
    gl_lds16(Kg + (long)row * 3072 + cs * 8, Ks + (i * 256 + wave * 64) * 8);
  }
  __syncthreads();  // #1: staged

  short8 aq[4][2], ak[4][2];
#pragma unroll
  for (int mi = 0; mi < 4; ++mi)
#pragma unroll
    for (int kk = 0; kk < 2; ++kk) {
      int sw = (((kk * 4 + quad) ^ (l16 & 7)) << 3);
      aq[mi][kk] = *(const short8*)(Qs + (mi * 16 + l16) * 64 + sw);
      ak[mi][kk] = *(const short8*)(Ks + (mi * 16 + l16) * 64 + sw);
    }
  __syncthreads();  // #2: fragments in regs; U reusable as CsT

  const floatx4 fzero = {0.f, 0.f, 0.f, 0.f};
  // ---- Gq slices (wave-strided) -> CsT ----
  for (int sl = wave; sl < nsl; sl += 4) {
    floatx4 g4[4];
#pragma unroll
    for (int mi = 0; mi < 4; ++mi) g4[mi] = fzero;
    int wrow = base + sl * 16 + l16;
#pragma unroll
    for (int kk = 0; kk < 2; ++kk) {
      short8 bp = *(const short8*)(posk_g + (long)wrow * 2048 + kk * 32 + quad * 8);
#pragma unroll
      for (int mi = 0; mi < 4; ++mi)
        g4[mi] = __builtin_amdgcn_mfma_f32_16x16x32_bf16(aq[mi][kk], bp, g4[mi], 0, 0, 0);
    }
#pragma unroll
    for (int mi = 0; mi < 4; ++mi) {
      uint2 t;
      t.x = pk2bf(g4[mi][0], g4[mi][1]);
      t.y = pk2bf(g4[mi][2], g4[mi][3]);
      *(uint2*)(CsT + (sl * 16 + l16) * 68 + mi * 16 + quad * 4) = t;
    }
  }
  // ---- Gk slices -> DsT ----
  for (int sl = wave; sl < nsl; sl += 4) {
    floatx4 g4[4];
#pragma unroll
    for (int mi = 0; mi < 4; ++mi) g4[mi] = fzero;
    int wrow = base + sl * 16 + l16;
#pragma unroll
    for (int kk = 0; kk < 2; ++kk) {
      short8 bp = *(const short8*)(posq_g + (long)wrow * 2048 + kk * 32 + quad * 8);
#pragma unroll
      for (int mi = 0; mi < 4; ++mi)
        g4[mi] = __builtin_amdgcn_mfma_f32_16x16x32_bf16(ak[mi][kk], bp, g4[mi], 0, 0, 0);
    }
#pragma unroll
    for (int mi = 0; mi < 4; ++mi) {
      uint2 t;
      t.x = pk2bf(g4[mi][0], g4[mi][1]);
      t.y = pk2bf(g4[mi][2], g4[mi][3]);
      *(uint2*)(DsT + (sl * 16 + l16) * 68 + mi * 16 + quad * 4) = t;
    }
  }
  __syncthreads();  // #3: windows complete

  // ---- gather + e5m2 store tile [64q][64k] (strided kloc, byte stores) ----
  const int qb4 = wave * 16 + quad * 4;
  u8* So = Sb + (long)g * (1024 * 1024) + (long)q0 * 1024 + k0;
#pragma unroll
  for (int ni = 0; ni < 4; ++ni) {
    int kloc = ni * 16 + l16;
#pragma unroll
    for (int r = 0; r < 4; ++r) {
      int dd = qb4 + r - kloc + 63;
      int off = lin ? dd : (int)offL[dd];
      float bias = bf2f(CsT[off * 68 + qb4 + r]) + bf2f(DsT[off * 68 + kloc]);
      So[(long)(qb4 + r) * 1024 + kloc] = f2e5(bias);
    }
  }
}

// ---------------- flash_lite: QBLK=128, 2-phase prefetch (r17) ---------------
// T3 minimum 2-phase: issue next tile's async staging BEFORE computing the
// current tile; ONE barrier/tile (its vmcnt(0) drain lands after ~700cy of
// compute -> stage latency hidden in-block). Double-buffered K/V/Bs; LDS
// 58.4 KB -> 2 blocks/CU; grid 512 = exactly-full residency (single round).
// K/V staged once per 128 q-rows (halved staging per unit work). Per wave:
// 2 q-strips sequential, Ps strip buffer reused (own-wave ordering).
__global__ __launch_bounds__(256, 2) void flash_lite(
    const u16* __restrict__ qkv, const u16* __restrict__ Vt,
    const u8* __restrict__ Sb, u16* __restrict__ ctx, float sc2) {
  __shared__ u16 Ks[2][64 * 64];
  __shared__ u16 Vs[2][64 * 64];   // [dd][k]
  __shared__ u8 Bs[2][128 * 64];   // bias tile [qloc][kloc] e5m2
  __shared__ u16 Ps[4][16 * 72];   // per-wave P strip (reused across strips)

  const int tid = threadIdx.x;
  const int wave = tid >> 6, lane = tid & 63;
  const int quad = lane >> 4, l16 = lane & 15;
  const int id = blockIdx.x;
  const int g = id & 63, qi = id >> 6;  // id%8==g%8 -> XCD affinity (qi in 0..7)
  const int b = g >> 4, h = g & 15, q0 = qi * 128;

  const u16* Kg = qkv + ((long)(b * S_LEN)) * 3072 + 1024 + h * HD;
  const u16* Vg = Vt + ((long)(b * NH + h) * HD) * S_LEN;
  const u8* Sg = Sb + (long)g * (1024 * 1024) + (long)q0 * 1024;

  // Q fragments for both strips, direct from global (once per block)
  short8 aqw[2][2];
#pragma unroll
  for (int s = 0; s < 2; ++s) {
    const u16* Qrow =
        qkv + ((long)(b * S_LEN + q0 + wave * 32 + s * 16 + l16)) * 3072 + h * HD;
    aqw[s][0] = *(const short8*)(Qrow + quad * 8);
    aqw[s][1] = *(const short8*)(Qrow + 32 + quad * 8);
  }

  const floatx4 fzero = {0.f, 0.f, 0.f, 0.f};
  floatx4 acc[2][4];
#pragma unroll
  for (int s = 0; s < 2; ++s)
#pragma unroll
    for (int ni = 0; ni < 4; ++ni) acc[s][ni] = fzero;
  float l_i[2][4] = {{0.f, 0.f, 0.f, 0.f}, {0.f, 0.f, 0.f, 0.f}};

  u16* Pw = &Ps[wave][0];

  // async stage of one 64-k tile into buffer `bu`
  auto STAGE = [&](int bu, int k0) {
#pragma unroll
    for (int i = 0; i < 2; ++i) {
      int ch = i * 256 + wave * 64 + lane;
      int row = ch >> 3, c = ch & 7, cs = c ^ (row & 7);
      gl_lds16(Kg + (long)(k0 + row) * 3072 + cs * 8,
               &Ks[bu][(i * 256 + wave * 64) * 8]);
      gl_lds16(Vg + (long)row * S_LEN + k0 + cs * 8,
               &Vs[bu][(i * 256 + wave * 64) * 8]);
    }
#pragma unroll
    for (int i = 0; i < 2; ++i) {
      int ch = i * 256 + wave * 64 + lane;
      int row = ch >> 2, c = ch & 3, cb = c ^ ((row >> 2) & 3);
      gl_lds16(Sg + (long)row * 1024 + k0 + cb * 16,
               &Bs[bu][(i * 256 + wave * 64) * 16]);
    }
  };

  STAGE(0, 0);
  __syncthreads();  // prologue drain: tile 0 ready
  int cur = 0;

  for (int t = 0; t < 16; ++t) {
    if (t < 15) STAGE(cur ^ 1, (t + 1) * 64);  // issue next tile (async)

    const u16* Kc = Ks[cur];
    const u16* Vc = Vs[cur];
    const u8* Bc = Bs[cur];

    // K fragments once per tile (shared by both strips)
    short8 ak[4][2];
#pragma unroll
    for (int ni = 0; ni < 4; ++ni)
#pragma unroll
      for (int kk = 0; kk < 2; ++kk) {
        int sw = (((kk * 4 + quad) ^ (l16 & 7)) << 3);
        ak[ni][kk] = *(const short8*)(Kc + (ni * 16 + l16) * 64 + sw);
      }

#pragma unroll
    for (int s = 0; s < 2; ++s) {
      const int qs = wave * 32 + s * 16 + quad * 4;
      // QK^T for this strip
      floatx4 sc[4];
#pragma unroll
      for (int ni = 0; ni < 4; ++ni) sc[ni] = fzero;
#pragma unroll
      for (int kk = 0; kk < 2; ++kk)
#pragma unroll
        for (int ni = 0; ni < 4; ++ni)
          sc[ni] = __builtin_amdgcn_mfma_f32_16x16x32_bf16(aqw[s][kk], ak[ni][kk],
                                                           sc[ni], 0, 0, 0);
      // bias + exp
      float pv[4][4];
#pragma unroll
      for (int ni = 0; ni < 4; ++ni) {
#pragma unroll
        for (int r = 0; r < 4; ++r) {
          int q = qs + r;
          u8 bb = Bc[q * 64 + ((ni ^ ((q >> 2) & 3)) << 4) + l16];
          pv[ni][r] = exp2f((sc[ni][r] + e52f(bb)) * sc2);
        }
      }
#pragma unroll
      for (int r = 0; r < 4; ++r) {
        float rs = pv[0][r] + pv[1][r] + pv[2][r] + pv[3][r];
        rs += __shfl_xor(rs, 1);
        rs += __shfl_xor(rs, 2);
        rs += __shfl_xor(rs, 4);
        rs += __shfl_xor(rs, 8);
        l_i[s][r] += rs;
      }
      // P: D-layout -> A-layout via per-wave strip (own-wave only)
#pragma unroll
      for (int ni = 0; ni < 4; ++ni)
#pragma unroll
        for (int r = 0; r < 4; ++r)
          Pw[(quad * 4 + r) * 72 + ni * 16 + l16] = f2bf(pv[ni][r]);

#pragma unroll
      for (int kk = 0; kk < 2; ++kk) {
        short8 ap = *(const short8*)(Pw + l16 * 72 + kk * 32 + quad * 8);
        int sw = (((kk * 4 + quad) ^ (l16 & 7)) << 3);
#pragma unroll
        for (int ni = 0; ni < 4; ++ni) {
          short8 vv = *(const short8*)(Vc + (ni * 16 + l16) * 64 + sw);
          acc[s][ni] = __builtin_amdgcn_mfma_f32_16x16x32_bf16(ap, vv, acc[s][ni], 0, 0, 0);
        }
      }
    }
    __syncthreads();  // drain prefetch (hidden under compute) + buffer handoff
    cur ^= 1;
  }

#pragma unroll
  for (int s = 0; s < 2; ++s)
#pragma unroll
    for (int ni = 0; ni < 4; ++ni) {
      int dd = ni * 16 + l16;
#pragma unroll
      for (int r = 0; r < 4; ++r) {
        int qrow = q0 + wave * 32 + s * 16 + quad * 4 + r;
        ctx[((long)(b * S_LEN) + qrow) * DMODEL + h * HD + dd] =
            f2bf(acc[s][ni][r] / l_i[s][r]);
      }
    }
}

// ---------------- LayerNorm over rows of 1024 ----------------
__global__ __launch_bounds__(256) void ln_kernel(
    const float* __restrict__ x, const float* __restrict__ gamma,
    const float* __restrict__ beta, float* __restrict__ out) {
  const int row = blockIdx.x;
  const int tid = threadIdx.x;
  const float* xr = x + (long)row * DMODEL;
  float4 v = *(const float4*)(xr + (tid << 2));
  float s = v.x + v.y + v.z + v.w;
#pragma unroll
  for (int off = 32; off; off >>= 1) s += __shfl_xor(s, off);
  __shared__ float red[4];
  if ((tid & 63) == 0) red[tid >> 6] = s;
  __syncthreads();
  float mu = (red[0] + red[1] + red[2] + red[3]) * (1.0f / DMODEL);
  float dx0 = v.x - mu, dx1 = v.y - mu, dx2 = v.z - mu, dx3 = v.w - mu;
  float sq = dx0 * dx0 + dx1 * dx1 + dx2 * dx2 + dx3 * dx3;
#pragma unroll
  for (int off = 32; off; off >>= 1) sq += __shfl_xor(sq, off);
  __syncthreads();
  if ((tid & 63) == 0) red[tid >> 6] = sq;
  __syncthreads();
  float var = (red[0] + red[1] + red[2] + red[3]) * (1.0f / DMODEL);
  float rstd = 1.0f / sqrtf(var + 1e-7f);
  float4 g = *(const float4*)(gamma + (tid << 2));
  float4 be = *(const float4*)(beta + (tid << 2));
  float4 o = make_float4(dx0 * rstd * g.x + be.x, dx1 * rstd * g.y + be.y,
                         dx2 * rstd * g.z + be.z, dx3 * rstd * g.w + be.w);
  *(float4*)(out + (long)row * DMODEL + (tid << 2)) = o;
}

extern "C" void kernel_launch(void* const* d_in, const int* in_sizes, int n_in,
                              void* d_out, int out_size, void* d_ws, size_t ws_size,
                              hipStream_t stream) {
  (void)in_sizes; (void)n_in; (void)out_size; (void)ws_size;
  const float* hidden = (const float*)d_in[0];
  const float* rel = (const float*)d_in[2];
  const float* Wq = (const float*)d_in[3];
  const float* bq = (const float*)d_in[4];
  const float* Wk = (const float*)d_in[5];
  const float* bk = (const float*)d_in[6];
  const float* Wv = (const float*)d_in[7];
  const float* bv = (const float*)d_in[8];
  const float* Wo = (const float*)d_in[9];
  const float* bo = (const float*)d_in[10];
  const float* gamma = (const float*)d_in[11];
  const float* beta = (const float*)d_in[12];
  float* out = (float*)d_out;

  char* p = (char*)d_ws;
  auto carve = [&](size_t bytes) -> char* {
    char* r = p;
    p += (bytes + 255) & ~(size_t)255;
    return r;
  };
  u16* hid_bf = (u16*)carve((size_t)4096 * 1024 * 2);
  u16* rel_bf = (u16*)carve((size_t)512 * 1024 * 2);
  u16* wqkv_bf = (u16*)carve((size_t)3072 * 1024 * 2);
  u16* wo_bf = (u16*)carve((size_t)1024 * 1024 * 2);
  u16* qkv_rm = (u16*)carve((size_t)4096 * 3072 * 2);   // [B*S, 3072] bf16
  // pos_rm before Vtb: gbias window B-reads may overrun by <=15 rows (never gathered)
  u16* pos_rm = (u16*)carve((size_t)512 * 2048 * 2);    // [512, 2048] bf16
  u16* Vtb = (u16*)carve((size_t)BATCH * NH * HD * S_LEN * 2);
  u16* ctx = (u16*)carve((size_t)4096 * 1024 * 2);
  float* tmp = (float*)carve((size_t)4096 * 1024 * 4);
  float* biascat = (float*)carve((size_t)3072 * 4);
  int* tab = (int*)carve((size_t)2047 * 4);
  u8* Sb = (u8*)carve((size_t)64 * 1024 * 1024);        // [64][1024][1024] e5m2

  const float inv_scale = 1.0f / sqrtf(192.0f);
  const float sc2 = inv_scale * 1.44269504088896f;  // fold log2(e): exp -> v_exp_f32

  cast_all<<<dim3(8720), dim3(256), 0, stream>>>(hidden, rel, Wq, Wk, Wv, Wo, hid_bf,
                                                 rel_bf, wqkv_bf, wo_bf, tab, bq, bk, bv,
                                                 biascat);

  // QKV + pos projections fused into one launch (T1 chunked XCD swizzle)
  mgemm_qkvpos<<<dim3(832), 256, 0, stream>>>(hid_bf, rel_bf, wqkv_bf, biascat,
                                              qkv_rm, pos_rm);

  // bias materialization (r13 frozen config) + V transpose in one launch
  gbias_vt<<<dim3(17408), 256, 0, stream>>>(qkv_rm, pos_rm, tab, Sb, Vtb);

  // flash attention: QBLK=128, double-buffered 2-phase prefetch, 512 blocks
  flash_lite<<<dim3(512), 256, 0, stream>>>(qkv_rm, Vtb, Sb, ctx, sc2);

  // out-proj + bias + residual (f32) at 2 blocks/CU, then LN
  mgemm_op<<<dim3(8, 64), 256, 0, stream>>>(ctx, wo_bf, bo, hidden, tmp, 4096, 1024, 1024);
  ln_kernel<<<dim3(4096), 256, 0, stream>>>(tmp, gamma, beta, out);
}

// Round 14
// 303.562 us; speedup vs baseline: 1.0149x; 1.0149x over previous
//
#include <hip/hip_runtime.h>
#include <math.h>

#define S_LEN 1024
#define DMODEL 1024
#define NH 16
#define HD 64
#define P2 512
#define BATCH 4

typedef unsigned short u16;
typedef unsigned char u8;
typedef __attribute__((ext_vector_type(8))) short short8;
typedef __attribute__((ext_vector_type(4))) float floatx4;

__device__ __forceinline__ u16 f2bf(float f) {
  unsigned u = __float_as_uint(f);
  unsigned r = u + 0x7FFFu + ((u >> 16) & 1u);
  return (u16)(r >> 16);
}
__device__ __forceinline__ float bf2f(u16 v) {
  return __uint_as_float(((unsigned)v) << 16);
}
__device__ __forceinline__ unsigned pk2bf(float a, float b) {
#if __has_builtin(__builtin_amdgcn_cvt_pk_bf16_f32)
  typedef __attribute__((ext_vector_type(2))) __bf16 bf2v;
  bf2v t = __builtin_amdgcn_cvt_pk_bf16_f32(a, b);
  return *(unsigned*)&t;
#else
  return (unsigned)f2bf(a) | ((unsigned)f2bf(b) << 16);
#endif
}
// e5m2-as-top-byte-of-f16: encode via v_cvt_f16_f32 (+round-half-up on bit 7)
__device__ __forceinline__ u8 f2e5(float x) {
  union { _Float16 h; u16 u; } c;
  c.h = (_Float16)x;
  return (u8)(((unsigned)c.u + 0x80u) >> 8);
}
__device__ __forceinline__ float e52f(u8 b) {
  union { u16 u; _Float16 h; } c;
  c.u = (u16)b << 8;
  return (float)c.h;
}
// async global->LDS, 16B per lane; lds dest = wave-uniform base + lane*16
__device__ __forceinline__ void gl_lds16(const void* g, void* l) {
  __builtin_amdgcn_global_load_lds(
      (const __attribute__((address_space(1))) void*)g,
      (__attribute__((address_space(3))) void*)l, 16, 0, 0);
}

// ---------------- fused cast + prep (tab/biascat in the tail blocks) ---------
__global__ __launch_bounds__(256) void cast_all(
    const float* __restrict__ h, const float* __restrict__ r,
    const float* __restrict__ wq, const float* __restrict__ wk,
    const float* __restrict__ wv, const float* __restrict__ wo,
    u16* __restrict__ hb, u16* __restrict__ rb,
    u16* __restrict__ wqkvb, u16* __restrict__ wob,
    int* __restrict__ tab, const float* __restrict__ bq,
    const float* __restrict__ bk, const float* __restrict__ bv,
    float* __restrict__ biascat) {
  int b = blockIdx.x;
  if (b >= 8704) {  // prep tail: 16 blocks
    int t = (b - 8704) * 256 + threadIdx.x;
    if (t < 2 * S_LEN - 1) {
      int rel = t - (S_LEN - 1);
      const int mid = 128;
      float abspos = (rel < mid && rel > -mid) ? (float)(mid - 1) : fabsf((float)rel);
      float bucket;
      if (abspos <= (float)mid) {
        bucket = (float)rel;
      } else {
        float den = (float)log(3.9921875);
        float lp = ceilf(logf(abspos / 128.0f) / den * 127.0f) + 128.0f;
        bucket = (rel > 0) ? lp : -lp;
      }
      int idx = (int)bucket + 256;
      idx = idx < 0 ? 0 : (idx > P2 - 1 ? P2 - 1 : idx);
      tab[t] = idx;
    }
    if (t < 3072) biascat[t] = t < 1024 ? bq[t] : (t < 2048 ? bk[t - 1024] : bv[t - 2048]);
    return;
  }
  const float* src;
  u16* dst;
  int off;
  if (b < 4096) { src = h; dst = hb; off = b; }
  else if (b < 4608) { src = r; dst = rb; off = b - 4096; }
  else if (b < 5632) { src = wq; dst = wqkvb; off = b - 4608; }
  else if (b < 6656) { src = wk; dst = wqkvb + 1024 * 1024; off = b - 5632; }
  else if (b < 7680) { src = wv; dst = wqkvb + 2 * 1024 * 1024; off = b - 6656; }
  else { src = wo; dst = wob; off = b - 7680; }
  long i = (long)off * 1024 + (threadIdx.x << 2);
  float4 v = *(const float4*)(src + i);
  uint2 o;
  o.x = pk2bf(v.x, v.y);
  o.y = pk2bf(v.z, v.w);
  *(uint2*)(dst + i) = o;
}

// ---------------- bf16 MFMA NT GEMM body, 128x128 tile, BK=64 (r11) ----------
// BK=64 halves barrier count; staging source chunk-swizzled (T2) so b128
// fragment reads are 2-way. LDS 32 KB (passed in).
// mode 0: f32 out + bias + resid. mode 1: bf16 row-major out + bias.
__device__ __forceinline__ void mgemm_body(
    u16* Al, u16* Bl, const u16* A, const u16* Bw,
    const float* b0, const float* resid, void* out0,
    int M, int N, int K, int mode, int bx, int by, int tid) {
  const int wave = tid >> 6, lane = tid & 63;
  const int quad = lane >> 4, l16 = lane & 15;
  const int m0 = by * 128, n0 = bx * 128;

  const floatx4 fzero = {0.f, 0.f, 0.f, 0.f};
  floatx4 acc[4][4];
#pragma unroll
  for (int mi = 0; mi < 4; ++mi)
#pragma unroll
    for (int ni = 0; ni < 4; ++ni) acc[mi][ni] = fzero;

  const int wm = (wave & 1) * 64, wn = (wave >> 1) * 64;

  for (int k0 = 0; k0 < K; k0 += 64) {
#pragma unroll
    for (int i = 0; i < 4; ++i) {
      int ch = i * 256 + tid;
      int row = ch >> 3, c = ch & 7, cs = c ^ (row & 7);
      gl_lds16(A + (long)(m0 + row) * K + k0 + cs * 8, Al + ch * 8);
      gl_lds16(Bw + (long)(n0 + row) * K + k0 + cs * 8, Bl + ch * 8);
    }
    __syncthreads();
    short8 af[4][2], bf[4][2];
#pragma unroll
    for (int t = 0; t < 4; ++t)
#pragma unroll
      for (int kk = 0; kk < 2; ++kk) {
        int sw = (((kk * 4 + quad) ^ (l16 & 7)) << 3);
        af[t][kk] = *(const short8*)(Al + (wm + t * 16 + l16) * 64 + sw);
        bf[t][kk] = *(const short8*)(Bl + (wn + t * 16 + l16) * 64 + sw);
      }
#pragma unroll
    for (int kk = 0; kk < 2; ++kk)
#pragma unroll
      for (int mi = 0; mi < 4; ++mi)
#pragma unroll
        for (int ni = 0; ni < 4; ++ni)
          acc[mi][ni] =
              __builtin_amdgcn_mfma_f32_16x16x32_bf16(af[mi][kk], bf[ni][kk], acc[mi][ni], 0, 0, 0);
    __syncthreads();
  }

  if (mode == 0) {
    float* o = (float*)out0;
#pragma unroll
    for (int mi = 0; mi < 4; ++mi)
#pragma unroll
      for (int ni = 0; ni < 4; ++ni) {
        int n = n0 + wn + ni * 16 + l16;
#pragma unroll
        for (int r = 0; r < 4; ++r) {
          int m = m0 + wm + mi * 16 + quad * 4 + r;
          o[(long)m * N + n] = acc[mi][ni][r] + b0[n] + resid[(long)m * N + n];
        }
      }
  } else {
    u16* o = (u16*)out0;
    u16* T = Al;  // 32 x 132 u16 = 8448 B (Al dead in epilogue)
    const int wp = wave & 1;
    float biasv[4];
#pragma unroll
    for (int ni = 0; ni < 4; ++ni) biasv[ni] = b0[n0 + wn + ni * 16 + l16];
#pragma unroll
    for (int p = 0; p < 4; ++p) {
#pragma unroll
      for (int ni = 0; ni < 4; ++ni) {
        int cl = wn + ni * 16 + l16;
#pragma unroll
        for (int r = 0; r < 4; ++r)
          T[(wp * 16 + quad * 4 + r) * 132 + cl] = f2bf(acc[p][ni][r] + biasv[ni]);
      }
      __syncthreads();
#pragma unroll
      for (int u = 0; u < 4; ++u) {
        int ch = u * 256 + tid;
        int row = ch >> 5, c4 = (ch & 31) << 2;
        int gr = m0 + (row >> 4) * 64 + p * 16 + (row & 15);
        *(ushort4*)(o + (long)gr * N + n0 + c4) = *(const ushort4*)(T + row * 132 + c4);
      }
      if (p < 3) __syncthreads();
    }
  }
}

// fused QKV + pos projections (T1 chunked XCD swizzle; measured neutral, free)
__global__ __launch_bounds__(256) void mgemm_qkvpos(
    const u16* __restrict__ hid, const u16* __restrict__ rel,
    const u16* __restrict__ wqkv, const float* __restrict__ biascat,
    u16* __restrict__ qkv, u16* __restrict__ posm) {
  __shared__ u16 Al[128 * 64];
  __shared__ u16 Bl[128 * 64];
  int id0 = blockIdx.x;
  int id = (id0 & 7) * 104 + (id0 >> 3);  // chunked per-XCD remap
  if (id < 768) {
    mgemm_body(Al, Bl, hid, wqkv, biascat, nullptr, qkv, 4096, 3072, 1024, 1,
               id % 24, id / 24, threadIdx.x);
  } else {
    int t = id - 768;
    mgemm_body(Al, Bl, rel, wqkv, biascat, nullptr, posm, 512, 2048, 1024, 1,
               t % 16, t / 16, threadIdx.x);
  }
}

// ---------------- out-proj GEMM: 64x128 tile, 2 blocks/CU (r15) --------------
__global__ __launch_bounds__(256) void mgemm_op(
    const u16* __restrict__ A, const u16* __restrict__ Bw,
    const float* __restrict__ b0, const float* __restrict__ resid,
    float* __restrict__ o, int M, int N, int K) {
  __shared__ u16 Al[64 * 64];    // A tile: 64 rows x 64 k
  __shared__ u16 Bl[128 * 64];   // B tile: 128 n-rows x 64 k
  const int tid = threadIdx.x;
  const int wave = tid >> 6, lane = tid & 63;
  const int quad = lane >> 4, l16 = lane & 15;
  const int m0 = blockIdx.y * 64, n0 = blockIdx.x * 128;
  const int wn = wave * 32;

  const floatx4 fzero = {0.f, 0.f, 0.f, 0.f};
  floatx4 acc[4][2];
#pragma unroll
  for (int mi = 0; mi < 4; ++mi)
#pragma unroll
    for (int ni = 0; ni < 2; ++ni) acc[mi][ni] = fzero;

  for (int k0 = 0; k0 < K; k0 += 64) {
#pragma unroll
    for (int i = 0; i < 2; ++i) {  // A: 64 rows x 8 chunks = 512
      int ch = i * 256 + tid;
      int row = ch >> 3, c = ch & 7, cs = c ^ (row & 7);
      gl_lds16(A + (long)(m0 + row) * K + k0 + cs * 8, Al + ch * 8);
    }
#pragma unroll
    for (int i = 0; i < 4; ++i) {  // B: 128 rows x 8 chunks = 1024
      int ch = i * 256 + tid;
      int row = ch >> 3, c = ch & 7, cs = c ^ (row & 7);
      gl_lds16(Bw + (long)(n0 + row) * K + k0 + cs * 8, Bl + ch * 8);
    }
    __syncthreads();
    short8 af[4][2], bf[2][2];
#pragma unroll
    for (int kk = 0; kk < 2; ++kk) {
      int sw = (((kk * 4 + quad) ^ (l16 & 7)) << 3);
#pragma unroll
      for (int t = 0; t < 4; ++t)
        af[t][kk] = *(const short8*)(Al + (t * 16 + l16) * 64 + sw);
#pragma unroll
      for (int ni = 0; ni < 2; ++ni)
        bf[ni][kk] = *(const short8*)(Bl + (wn + ni * 16 + l16) * 64 + sw);
    }
#pragma unroll
    for (int kk = 0; kk < 2; ++kk)
#pragma unroll
      for (int mi = 0; mi < 4; ++mi)
#pragma unroll
        for (int ni = 0; ni < 2; ++ni)
          acc[mi][ni] =
              __builtin_amdgcn_mfma_f32_16x16x32_bf16(af[mi][kk], bf[ni][kk], acc[mi][ni], 0, 0, 0);
    __syncthreads();
  }

#pragma unroll
  for (int mi = 0; mi < 4; ++mi)
#pragma unroll
    for (int ni = 0; ni < 2; ++ni) {
      int n = n0 + wn + ni * 16 + l16;
#pragma unroll
      for (int r = 0; r < 4; ++r) {
        int m = m0 + mi * 16 + quad * 4 + r;
        o[(long)m * N + n] = acc[mi][ni][r] + b0[n] + resid[(long)m * N + n];
      }
    }
}

// ---------------- gbias (r9/r13 measured-best, FROZEN) + vtrans tail ---------
// Every deviation from this config failed (r10 packed stores, r11 stride-70,
// r12 merged loops, r14 e5m2-LDS/6-blocks-CU): bf16 windows stride 68,
// separate Gq/Gk loops, strided-k gather, scalar byte stores, 4 blocks/CU.
// blocks [16384,17408): V transpose (tile aliases U).
__global__ __launch_bounds__(256, 4) void gbias_vt(
    const u16* __restrict__ qkv, const u16* __restrict__ pos,
    const int* __restrict__ tab, u8* __restrict__ Sb, u16* __restrict__ Vt) {
  __shared__ u16 U[128 * 68];    // phase 1: Qs/Ks; phase 2: CsT; vtrans: tile
  __shared__ u16 DsT[128 * 68];  // Gk^T [off][kloc]
  __shared__ u16 offL[128];

  const int tid = threadIdx.x;
  const int id = blockIdx.x;

  if (id >= 16384) {  // ---- vtrans tail ----
    int v = id - 16384;
    const int s0 = (v & 15) * 64, h = (v >> 4) & 15, b = v >> 8;
    u16(*tile)[68] = (u16(*)[68])U;  // 64x68 u16 = 8704 B
    const int r16 = tid >> 4, c4 = (tid & 15) << 2;
    const u16* src = qkv + ((long)(b * S_LEN + s0)) * 3072 + 2048 + h * HD;
#pragma unroll
    for (int i = 0; i < 4; ++i) {
      int row = i * 16 + r16;
      ushort4 vv = *(const ushort4*)(src + (long)row * 3072 + c4);
      *(ushort4*)&tile[row][c4] = vv;
    }
    __syncthreads();
    u16* dst = Vt + ((long)(b * NH + h) * HD) * S_LEN + s0;
#pragma unroll
    for (int i = 0; i < 4; ++i) {
      int dd = i * 16 + r16;
      ushort4 o;
      o.x = tile[c4 + 0][dd]; o.y = tile[c4 + 1][dd];
      o.z = tile[c4 + 2][dd]; o.w = tile[c4 + 3][dd];
      *(ushort4*)(dst + (long)dd * S_LEN + c4) = o;
    }
    return;
  }

  u16* Qs = U;
  u16* Ks = U + 64 * 64;
  u16* CsT = U;

  const int wave = tid >> 6, lane = tid & 63;
  const int quad = lane >> 4, l16 = lane & 15;
  const int g = id & 63, tt = id >> 6;  // id%8==g%8 -> XCD affinity
  const int qi = tt >> 4, ki = tt & 15;
  const int b = g >> 4, h = g & 15;
  const int q0 = qi * 64, k0 = ki * 64;

  const u16* Qg = qkv + ((long)(b * S_LEN + q0)) * 3072 + h * HD;
  const u16* Kg = qkv + ((long)(b * S_LEN + k0)) * 3072 + 1024 + h * HD;
  const u16* posq_g = pos + h * HD;         // Wq-proj cols
  const u16* posk_g = pos + 1024 + h * HD;  // Wk-proj cols

  const int dmin = q0 - k0 - 63;
  const int base = tab[dmin + 1023];
  const int w = tab[dmin + 1149] - base + 1;  // monotone => 1..127
  const int nsl = (w + 15) >> 4;
  const bool lin = (w == 127);
  if (!lin && tid < 127) offL[tid] = (u16)(tab[dmin + 1023 + tid] - base);

  // stage Q,K async; source chunk-swizzled (c ^ row&7) for 2-way b128 reads
#pragma unroll
  for (int i = 0; i < 2; ++i) {
    int ch = i * 256 + wave * 64 + lane;
    int row = ch >> 3, c = ch & 7, cs = c ^ (row & 7);
    gl_lds16(Qg + (long)row * 3072 + cs * 8, Qs + (i * 256 + wave * 64) * 8);
    gl_lds16(Kg + (long)row * 3072 + cs * 8, Ks + (i * 256 + wave * 64) * 8);
  }
  __syncthreads();  // #1: staged

  short8 aq[4][2], ak[4][2];
#pragma unroll
  for (int mi = 0; mi < 4; ++mi)
#pragma unroll
    for (int kk = 0; kk < 2; ++kk) {
      int sw = (((kk * 4 + quad) ^ (l16 & 7)) << 3);
      aq[mi][kk] = *(const short8*)(Qs + (mi * 16 + l16) * 64 + sw);
      ak[mi][kk] = *(const short8*)(Ks + (mi * 16 + l16) * 64 + sw);
    }
  __syncthreads();  // #2: fragments in regs; U reusable as CsT

  const floatx4 fzero = {0.f, 0.f, 0.f, 0.f};
  // ---- Gq slices (wave-strided) -> CsT ----
  for (int sl = wave; sl < nsl; sl += 4) {
    floatx4 g4[4];
#pragma unroll
    for (int mi = 0; mi < 4; ++mi) g4[mi] = fzero;
    int wrow = base + sl * 16 + l16;
#pragma unroll
    for (int kk = 0; kk < 2; ++kk) {
      short8 bp = *(const short8*)(posk_g + (long)wrow * 2048 + kk * 32 + quad * 8);
#pragma unroll
      for (int mi = 0; mi < 4; ++mi)
        g4[mi] = __builtin_amdgcn_mfma_f32_16x16x32_bf16(aq[mi][kk], bp, g4[mi], 0, 0, 0);
    }
#pragma unroll
    for (int mi = 0; mi < 4; ++mi) {
      uint2 t;
      t.x = pk2bf(g4[mi][0], g4[mi][1]);
      t.y = pk2bf(g4[mi][2], g4[mi][3]);
      *(uint2*)(CsT + (sl * 16 + l16) * 68 + mi * 16 + quad * 4) = t;
    }
  }
  // ---- Gk slices -> DsT ----
  for (int sl = wave; sl < nsl; sl += 4) {
    floatx4 g4[4];
#pragma unroll
    for (int mi = 0; mi < 4; ++mi) g4[mi] = fzero;
    int wrow = base + sl * 16 + l16;
#pragma unroll
    for (int kk = 0; kk < 2; ++kk) {
      short8 bp = *(const short8*)(posq_g + (long)wrow * 2048 + kk * 32 + quad * 8);
#pragma unroll
      for (int mi = 0; mi < 4; ++mi)
        g4[mi] = __builtin_amdgcn_mfma_f32_16x16x32_bf16(ak[mi][kk], bp, g4[mi], 0, 0, 0);
    }
#pragma unroll
    for (int mi = 0; mi < 4; ++mi) {
      uint2 t;
      t.x = pk2bf(g4[mi][0], g4[mi][1]);
      t.y = pk2bf(g4[mi][2], g4[mi][3]);
      *(uint2*)(DsT + (sl * 16 + l16) * 68 + mi * 16 + quad * 4) = t;
    }
  }
  __syncthreads();  // #3: windows complete

  // ---- gather + e5m2 store tile [64q][64k] (strided kloc, byte stores) ----
  const int qb4 = wave * 16 + quad * 4;
  u8* So = Sb + (long)g * (1024 * 1024) + (long)q0 * 1024 + k0;
#pragma unroll
  for (int ni = 0; ni < 4; ++ni) {
    int kloc = ni * 16 + l16;
#pragma unroll
    for (int r = 0; r < 4; ++r) {
      int dd = qb4 + r - kloc + 63;
      int off = lin ? dd : (int)offL[dd];
      float bias = bf2f(CsT[off * 68 + qb4 + r]) + bf2f(DsT[off * 68 + kloc]);
      So[(long)(qb4 + r) * 1024 + kloc] = f2e5(bias);
    }
  }
}

// ---------------- flash_lite (r15 measured-best): QBLK=64, 4 blocks/CU -------
// r17's QBLK=128 2-phase variant was neutral-to-negative (TLP at 4 blocks/CU
// already hides stage latency); this config is the measured optimum.
__global__ __launch_bounds__(256, 4) void flash_lite(
    const u16* __restrict__ qkv, const u16* __restrict__ Vt,
    const u8* __restrict__ Sb, u16* __restrict__ ctx, float sc2) {
  __shared__ u16 Ks[64 * 64];
  __shared__ u16 Vs[64 * 64];     // [dd][k]
  __shared__ u8 Bs[64 * 64];      // bias tile [qloc][kloc] e5m2
  __shared__ u16 Ps[4][16 * 72];  // per-wave P strip

  const int tid = threadIdx.x;
  const int wave = tid >> 6, lane = tid & 63;
  const int quad = lane >> 4, l16 = lane & 15;
  const int id = blockIdx.x;
  const int g = id & 63, qi = id >> 6;  // id%8==g%8 -> XCD affinity
  const int b = g >> 4, h = g & 15, q0 = qi * 64;

  const u16* Kg = qkv + ((long)(b * S_LEN)) * 3072 + 1024 + h * HD;
  const u16* Vg = Vt + ((long)(b * NH + h) * HD) * S_LEN;
  const u8* Sg = Sb + (long)g * (1024 * 1024) + (long)q0 * 1024;

  // own-strip Q fragments direct from global (once per block)
  short8 aqw[2];
  {
    const u16* Qrow = qkv + ((long)(b * S_LEN + q0 + wave * 16 + l16)) * 3072 + h * HD;
    aqw[0] = *(const short8*)(Qrow + quad * 8);
    aqw[1] = *(const short8*)(Qrow + 32 + quad * 8);
  }

  const floatx4 fzero = {0.f, 0.f, 0.f, 0.f};
  floatx4 acc[4];
#pragma unroll
  for (int ni = 0; ni < 4; ++ni) acc[ni] = fzero;
  float l_i[4] = {0.f, 0.f, 0.f, 0.f};

  u16* Pw = &Ps[wave][0];
  const int qb4 = wave * 16 + quad * 4;

  for (int k0 = 0; k0 < S_LEN; k0 += 64) {
#pragma unroll
    for (int i = 0; i < 2; ++i) {
      int ch = i * 256 + wave * 64 + lane;
      int row = ch >> 3, c = ch & 7;
      int cs = c ^ (row & 7);          // key for b128 frag reads (K,V)
      gl_lds16(Kg + (long)(k0 + row) * 3072 + cs * 8, Ks + (i * 256 + wave * 64) * 8);
      gl_lds16(Vg + (long)row * S_LEN + k0 + cs * 8, Vs + (i * 256 + wave * 64) * 8);
    }
    {
      // bias tile: 4KB = one 256-lane round; 64B rows = 4 chunks of 16B;
      // chunk swizzled by ((row>>2)&3) so the 4 quads of a gather instruction
      // (rows q,q+4,q+8,q+12) hit different bank groups.
      int row = tid >> 2, c = tid & 3;
      int cb = c ^ ((row >> 2) & 3);
      gl_lds16(Sg + (long)row * 1024 + k0 + cb * 16, Bs + (wave << 10));
    }
    __syncthreads();  // #1: tiles staged

    // QK^T for this wave's q-strip
    floatx4 s[4];
#pragma unroll
    for (int ni = 0; ni < 4; ++ni) s[ni] = fzero;
#pragma unroll
    for (int kk = 0; kk < 2; ++kk) {
      int sw = (((kk * 4 + quad) ^ (l16 & 7)) << 3);
#pragma unroll
      for (int ni = 0; ni < 4; ++ni) {
        short8 ak = *(const short8*)(Ks + (ni * 16 + l16) * 64 + sw);
        s[ni] = __builtin_amdgcn_mfma_f32_16x16x32_bf16(aqw[kk], ak, s[ni], 0, 0, 0);
      }
    }

    // bias + exp
    float pv[4][4];
#pragma unroll
    for (int ni = 0; ni < 4; ++ni) {
#pragma unroll
      for (int r = 0; r < 4; ++r) {
        int q = qb4 + r;
        int kloc = ni * 16 + l16;
        u8 bb = Bs[q * 64 + (((kloc >> 4) ^ ((q >> 2) & 3)) << 4) + (kloc & 15)];
        pv[ni][r] = exp2f((s[ni][r] + e52f(bb)) * sc2);
      }
    }
#pragma unroll
    for (int r = 0; r < 4; ++r) {
      float rs = pv[0][r] + pv[1][r] + pv[2][r] + pv[3][r];
      rs += __shfl_xor(rs, 1);
      rs += __shfl_xor(rs, 2);
      rs += __shfl_xor(rs, 4);
      rs += __shfl_xor(rs, 8);
      l_i[r] += rs;
    }
    // P: D-layout -> A-layout via per-wave strip (own-wave only, no barrier)
#pragma unroll
    for (int ni = 0; ni < 4; ++ni)
#pragma unroll
      for (int r = 0; r < 4; ++r)
        Pw[(quad * 4 + r) * 72 + ni * 16 + l16] = f2bf(pv[ni][r]);

#pragma unroll
    for (int kk = 0; kk < 2; ++kk) {
      short8 ap = *(const short8*)(Pw + l16 * 72 + kk * 32 + quad * 8);
      int sw = (((kk * 4 + quad) ^ (l16 & 7)) << 3);
#pragma unroll
      for (int ni = 0; ni < 4; ++ni) {
        short8 vv = *(const short8*)(Vs + (ni * 16 + l16) * 64 + sw);
        acc[ni] = __builtin_amdgcn_mfma_f32_16x16x32_bf16(ap, vv, acc[ni], 0, 0, 0);
      }
    }
    __syncthreads();  // #2: all reads done before next tile overwrites
  }

#pragma unroll
  for (int ni = 0; ni < 4; ++ni) {
    int dd = ni * 16 + l16;
#pragma unroll
    for (int r = 0; r < 4; ++r) {
      int qrow = q0 + qb4 + r;
      ctx[((long)(b * S_LEN) + qrow) * DMODEL + h * HD + dd] = f2bf(acc[ni][r] / l_i[r]);
    }
  }
}

// ---------------- LayerNorm over rows of 1024 ----------------
__global__ __launch_bounds__(256) void ln_kernel(
    const float* __restrict__ x, const float* __restrict__ gamma,
    const float* __restrict__ beta, float* __restrict__ out) {
  const int row = blockIdx.x;
  const int tid = threadIdx.x;
  const float* xr = x + (long)row * DMODEL;
  float4 v = *(const float4*)(xr + (tid << 2));
  float s = v.x + v.y + v.z + v.w;
#pragma unroll
  for (int off = 32; off; off >>= 1) s += __shfl_xor(s, off);
  __shared__ float red[4];
  if ((tid & 63) == 0) red[tid >> 6] = s;
  __syncthreads();
  float mu = (red[0] + red[1] + red[2] + red[3]) * (1.0f / DMODEL);
  float dx0 = v.x - mu, dx1 = v.y - mu, dx2 = v.z - mu, dx3 = v.w - mu;
  float sq = dx0 * dx0 + dx1 * dx1 + dx2 * dx2 + dx3 * dx3;
#pragma unroll
  for (int off = 32; off; off >>= 1) sq += __shfl_xor(sq, off);
  __syncthreads();
  if ((tid & 63) == 0) red[tid >> 6] = sq;
  __syncthreads();
  float var = (red[0] + red[1] + red[2] + red[3]) * (1.0f / DMODEL);
  float rstd = 1.0f / sqrtf(var + 1e-7f);
  float4 g = *(const float4*)(gamma + (tid << 2));
  float4 be = *(const float4*)(beta + (tid << 2));
  float4 o = make_float4(dx0 * rstd * g.x + be.x, dx1 * rstd * g.y + be.y,
                         dx2 * rstd * g.z + be.z, dx3 * rstd * g.w + be.w);
  *(float4*)(out + (long)row * DMODEL + (tid << 2)) = o;
}

extern "C" void kernel_launch(void* const* d_in, const int* in_sizes, int n_in,
                              void* d_out, int out_size, void* d_ws, size_t ws_size,
                              hipStream_t stream) {
  (void)in_sizes; (void)n_in; (void)out_size; (void)ws_size;
  const float* hidden = (const float*)d_in[0];
  const float* rel = (const float*)d_in[2];
  const float* Wq = (const float*)d_in[3];
  const float* bq = (const float*)d_in[4];
  const float* Wk = (const float*)d_in[5];
  const float* bk = (const float*)d_in[6];
  const float* Wv = (const float*)d_in[7];
  const float* bv = (const float*)d_in[8];
  const float* Wo = (const float*)d_in[9];
  const float* bo = (const float*)d_in[10];
  const float* gamma = (const float*)d_in[11];
  const float* beta = (const float*)d_in[12];
  float* out = (float*)d_out;

  char* p = (char*)d_ws;
  auto carve = [&](size_t bytes) -> char* {
    char* r = p;
    p += (bytes + 255) & ~(size_t)255;
    return r;
  };
  u16* hid_bf = (u16*)carve((size_t)4096 * 1024 * 2);
  u16* rel_bf = (u16*)carve((size_t)512 * 1024 * 2);
  u16* wqkv_bf = (u16*)carve((size_t)3072 * 1024 * 2);
  u16* wo_bf = (u16*)carve((size_t)1024 * 1024 * 2);
  u16* qkv_rm = (u16*)carve((size_t)4096 * 3072 * 2);   // [B*S, 3072] bf16
  // pos_rm before Vtb: gbias window B-reads may overrun by <=15 rows (never gathered)
  u16* pos_rm = (u16*)carve((size_t)512 * 2048 * 2);    // [512, 2048] bf16
  u16* Vtb = (u16*)carve((size_t)BATCH * NH * HD * S_LEN * 2);
  u16* ctx = (u16*)carve((size_t)4096 * 1024 * 2);
  float* tmp = (float*)carve((size_t)4096 * 1024 * 4);
  float* biascat = (float*)carve((size_t)3072 * 4);
  int* tab = (int*)carve((size_t)2047 * 4);
  u8* Sb = (u8*)carve((size_t)64 * 1024 * 1024);        // [64][1024][1024] e5m2

  const float inv_scale = 1.0f / sqrtf(192.0f);
  const float sc2 = inv_scale * 1.44269504088896f;  // fold log2(e): exp -> v_exp_f32

  cast_all<<<dim3(8720), dim3(256), 0, stream>>>(hidden, rel, Wq, Wk, Wv, Wo, hid_bf,
                                                 rel_bf, wqkv_bf, wo_bf, tab, bq, bk, bv,
                                                 biascat);

  // QKV + pos projections fused into one launch (T1 chunked XCD swizzle)
  mgemm_qkvpos<<<dim3(832), 256, 0, stream>>>(hid_bf, rel_bf, wqkv_bf, biascat,
                                              qkv_rm, pos_rm);

  // bias materialization (r13 frozen config) + V transpose in one launch
  gbias_vt<<<dim3(17408), 256, 0, stream>>>(qkv_rm, pos_rm, tab, Sb, Vtb);
  flash_lite<<<dim3(1024), 256, 0, stream>>>(qkv_rm, Vtb, Sb, ctx, sc2);

  // out-proj + bias + residual (f32) at 2 blocks/CU, then LN
  mgemm_op<<<dim3(8, 64), 256, 0, stream>>>(ctx, wo_bf, bo, hidden, tmp, 4096, 1024, 1024);
  ln_kernel<<<dim3(4096), 256, 0, stream>>>(tmp, gamma, beta, out);
}